// Round 8
// baseline (233.481 us; speedup 1.0000x reference)
//
#include <hip/hip_runtime.h>
#include <math.h>

// Problem constants (fixed by reference)
#define NF 8
#define NK 16
#define BB 32
#define YY 32
#define XX 32
#define PP 16
#define TT 8
#define YX (YY*XX)     // 1024
#define PT (PP*TT)     // 128
#define YXPT (YX*PT)   // 131072
#define CHUNKS 8
#define COLS_PER_BLOCK (YX/CHUNKS)        // 128
#define COLS_PER_WAVE  (COLS_PER_BLOCK/4) // 32
#define STEP           ((2*PT)/4)         // 64 float4s = 2 columns

// Workspace layout (float offsets)
// ACC : [CHUNKS][BB*NF*NK] feature partials            = 32768
// ACCQ: [CHUNKS*BB][NF*NK] integral partials (w*quad)  = 32768
#define ACC_OFF   0
#define ACCQ_OFF  (CHUNKS*BB*NF*NK)

// ---------------------------------------------------------------------------
// K1: main contraction + FUSED integral partials. Two dispatches total.
//
//  R8 RATIONALE: R7 nulled the occupancy theory (waves_per_eu(4): no change
//  vs R5 -> occupancy 2 vs 4 waves/SIMD indistinguishable). Corrected
//  accounting: k_main ~61us AND k_qmean ~8us both stream at ~2.2 TB/s --
//  shared ceiling from the harness poison fill leaving 256MB of DIRTY L3:
//  every read miss forces a dirty eviction writeback (~1 WB byte per read
//  byte), so k_main's true traffic is ~140R + ~134W = 274 MB -> ~50us
//  roofline. k_main is within ~20% of that. The remaining controllable cost
//  is qmean(8) + integral(2.5) + 2 launch gaps (~4) = ~15us -> FUSE:
//  integral[f,k] = (1/B) sum_b sum_yxpt w * quad_b  (== sum w*qmean;
//  numerics PROVEN in R1, absmax 0.0). R1's version spilled only because of
//  the 84-VGPR launch_bounds cap; uncapped (R6: 188 VGPR) does not spill,
//  and accq[16] + 3 extra FMA/k/col-pair rides on top of Horner's savings.
//
//  Carried verified decisions:
//  - __launch_bounds__(256) PLAIN, NO waves_per_eu. (256,3) -> 84-VGPR cap
//    spill disaster (R1/R2); waves_per_eu(4) -> no effect (R7). Uncapped
//    <=188 VGPR does not spill (R6).
//  - distance-4 pipeline (R6's distance-8 REGRESSED).
//  - Horner/separability: dot(v, wf[k]) = c_k * Horner(v, r_k); r[k]
//    wave-uniform -> SGPR via readfirstlane; c_k applied in epilogue from
//    LDS (never live across the loop). Applies to BOTH acc and accq.
//  - XCD-aware remap: 8 f-sharers of one quad slice -> same XCD L2
//    (R2-verified: FETCH 139.5 MB ~= ideal).
//  - sw/wptab/prm tables built inline in LDS (verified numerics).
//  - plain loads only (nontemporal bypasses L2 merging -> 8x over-fetch).
// ---------------------------------------------------------------------------

#define KQ(WC, K) do {                                                          \
    float poly = fmaf(ga.w, r[K], ga.z);                                        \
    poly = fmaf(poly, r[K], ga.y);                                              \
    poly = fmaf(poly, r[K], ga.x);                                              \
    acc[K] = fmaf(WC, poly, acc[K]);                                            \
    float pq = fmaf(qa.w, r[K], qa.z);                                          \
    pq = fmaf(pq, r[K], qa.y);                                                  \
    pq = fmaf(pq, r[K], qa.x);                                                  \
    accq[K] = fmaf(WC, pq, accq[K]);                                            \
} while (0)

#define COLPAIR_COMPUTE(WVP) do {                                               \
    float4 ga;                                                                  \
    ga.x = fa.x*qa.x; ga.y = fa.y*qa.y; ga.z = fa.z*qa.z; ga.w = fa.w*qa.w;     \
    float4 w0 = (WVP)[0], w1 = (WVP)[1], w2 = (WVP)[2], w3 = (WVP)[3];          \
    KQ(w0.x, 0);  KQ(w0.y, 1);  KQ(w0.z, 2);  KQ(w0.w, 3);                      \
    KQ(w1.x, 4);  KQ(w1.y, 5);  KQ(w1.z, 6);  KQ(w1.w, 7);                      \
    KQ(w2.x, 8);  KQ(w2.y, 9);  KQ(w2.z, 10); KQ(w2.w, 11);                     \
    KQ(w3.x, 12); KQ(w3.y, 13); KQ(w3.z, 14); KQ(w3.w, 15);                     \
} while (0)

__global__ __launch_bounds__(256) void k_main(
    const float* __restrict__ field, const float* __restrict__ quad,
    const float* __restrict__ mean_lat, const float* __restrict__ logstd_lat,
    const float* __restrict__ mean_lon, const float* __restrict__ logstd_lon,
    const float* __restrict__ mean_lev, const float* __restrict__ logstd_lev,
    const float* __restrict__ logtau, float* __restrict__ ws)
{
    const int bx = blockIdx.x;
    // XCD-aware remap: 8 f-sharers of one quad slice -> same XCD L2
    const int qg2 = bx >> 6, f = (bx >> 3) & 7, rr0 = bx & 7;
    const int bc = qg2 * 8 + rr0;
    const int b = bc >> 3, chunk = bc & 7;
    const int tid = threadIdx.x;
    const int wave = tid >> 6, L = tid & 63;
    const int half = L >> 5, qg = L & 31;

    const int colBase = chunk * COLS_PER_BLOCK + wave * COLS_PER_WAVE;
    const float4* fp = (const float4*)(field + (size_t)(b * NF + f) * YXPT + (size_t)colBase * PT) + L;
    const float4* qp = (const float4*)(quad  + (size_t)b * YXPT            + (size_t)colBase * PT) + L;

    // issue prologue global loads FIRST: they fly during the LDS table build
    float4 fbuf[4], qbuf[4];
    #pragma unroll
    for (int j = 0; j < 4; ++j) { fbuf[j] = fp[j * STEP]; qbuf[j] = qp[j * STEP]; }

    __shared__ __align__(16) float sw[COLS_PER_BLOCK * NK]; // 8 KB: [col][k]
    __shared__ float wptab[NK * PP];                        // 1 KB: [k][p]
    __shared__ float prm[NK][8];

    if (tid < NK) {
        const int fk = f * NK + tid;
        prm[tid][0] = mean_lat[fk];
        prm[tid][1] = expf(-logstd_lat[fk]);            // 1/std lat
        prm[tid][2] = mean_lon[fk];
        prm[tid][3] = expf(-logstd_lon[fk]);
        prm[tid][4] = mean_lev[fk];
        prm[tid][5] = expf(-logstd_lev[fk]);
        const float itau = 1.f / (expf(logtau[fk]) + 1e-4f);
        const float rk = expf(-itau);
        prm[tid][6] = rk;                               // r = exp(-1/tau)
        prm[tid][7] = rk * rk * rk * rk;                // r^4
    }
    __syncthreads();

    #pragma unroll
    for (int i = 0; i < 8; ++i) {       // sw[col][k] for this chunk
        const int e = i * 256 + tid;
        const int col = e >> 4, k = e & 15;
        const int yx = chunk * COLS_PER_BLOCK + col;
        const float cy = -1.f + 2.f * (float)(yx >> 5) / (YY - 1);
        const float cx = -1.f + 2.f * (float)(yx & 31) / (XX - 1);
        const float zy = (cy - prm[k][0]) * prm[k][1];
        const float zx = (cx - prm[k][2]) * prm[k][3];
        sw[col * NK + k] = expf(-0.5f * (zy * zy + zx * zx));
    }
    {   // wptab[k][p]: one expf per thread
        const int k = tid >> 4, p = tid & 15;
        const float cp = -1.f + 2.f * (float)p / (PP - 1);
        const float zp = (cp - prm[k][4]) * prm[k][5];
        wptab[tid] = expf(-0.5f * zp * zp);
    }
    __syncthreads();

    // r[k] is wave-uniform -> pin to SGPRs (v_fma takes one SGPR operand)
    float r[NK];
    #pragma unroll
    for (int k = 0; k < NK; ++k)
        r[k] = __int_as_float(__builtin_amdgcn_readfirstlane(__float_as_int(prm[k][6])));

    float acc[NK], accq[NK];
    #pragma unroll
    for (int k = 0; k < NK; ++k) { acc[k] = 0.f; accq[k] = 0.f; }

    const float* swp = sw + (wave * COLS_PER_WAVE + half) * NK;

    // distance-4 pipeline, inner-unroll-4, peeled tail (no OOB prefetch)
    #pragma unroll 1
    for (int so = 0; so < 3; ++so) {
        fp += 4 * STEP; qp += 4 * STEP;
        #pragma unroll
        for (int j = 0; j < 4; ++j) {
            float4 fa = fbuf[j], qa = qbuf[j];
            fbuf[j] = fp[j * STEP]; qbuf[j] = qp[j * STEP];
            const float4* wvp = (const float4*)(swp + j * (2 * NK));
            COLPAIR_COMPUTE(wvp);
        }
        swp += 4 * (2 * NK);
    }
    #pragma unroll
    for (int j = 0; j < 4; ++j) {
        float4 fa = fbuf[j], qa = qbuf[j];
        const float4* wvp = (const float4*)(swp + j * (2 * NK));
        COLPAIR_COMPUTE(wvp);
    }

    // epilogue: apply factored per-lane constant c_k = wp[k][p] * r^t0
    // (computed HERE from LDS so it is never live across the main loop)
    {
        const int p = qg >> 1, hi = qg & 1;
        #pragma unroll
        for (int k = 0; k < NK; ++k) {
            const float wp = wptab[k * PP + p];
            const float ck = hi ? wp * prm[k][7] : wp;
            acc[k] *= ck;
            accq[k] *= ck;
        }
    }

    __shared__ float red[4][NK], redq[4][NK];
    #pragma unroll
    for (int k = 0; k < NK; ++k) {
        float v = acc[k];
        v += __shfl_xor(v, 32); v += __shfl_xor(v, 16); v += __shfl_xor(v, 8);
        v += __shfl_xor(v, 4);  v += __shfl_xor(v, 2);  v += __shfl_xor(v, 1);
        float vq = accq[k];
        vq += __shfl_xor(vq, 32); vq += __shfl_xor(vq, 16); vq += __shfl_xor(vq, 8);
        vq += __shfl_xor(vq, 4);  vq += __shfl_xor(vq, 2);  vq += __shfl_xor(vq, 1);
        if (L == 0) { red[wave][k] = v; redq[wave][k] = vq; }
    }
    __syncthreads();
    if (tid < NK) {
        float s2 = red[0][tid] + red[1][tid] + red[2][tid] + red[3][tid];
        ws[ACC_OFF + chunk * (BB * NF * NK) + (b * NF + f) * NK + tid] = s2;
    } else if (tid >= 64 && tid < 64 + NK) {
        const int k = tid - 64;
        float s2 = redq[0][k] + redq[1][k] + redq[2][k] + redq[3][k];
        ws[ACCQ_OFF + (chunk * BB + b) * (NF * NK) + f * NK + k] = s2;
    }
}

// ---------------------------------------------------------------------------
// K2: integral[f,k] = 1e-4 + (sum_{chunk,b} accq) / B ; out = accSum / integral
// ---------------------------------------------------------------------------
__global__ __launch_bounds__(256) void k_final(const float* __restrict__ ws,
                                               float* __restrict__ out) {
    __shared__ float intg[NF * NK];
    const int tid = threadIdx.x;
    const int i = blockIdx.x * 256 + tid;
    if (tid < NF * NK) {
        float g = 0.f;
        #pragma unroll 8
        for (int cb = 0; cb < CHUNKS * BB; ++cb)
            g += ws[ACCQ_OFF + cb * (NF * NK) + tid];
        intg[tid] = 1e-4f + g * (1.f / BB);
    }
    __syncthreads();
    float a = 0.f;
    #pragma unroll
    for (int c = 0; c < CHUNKS; ++c) a += ws[ACC_OFF + c * (BB * NF * NK) + i];
    out[i] = a / intg[i & (NF * NK - 1)];
}

extern "C" void kernel_launch(void* const* d_in, const int* in_sizes, int n_in,
                              void* d_out, int out_size, void* d_ws, size_t ws_size,
                              hipStream_t stream) {
    const float* field = (const float*)d_in[0];
    const float* quad  = (const float*)d_in[1];
    float* ws = (float*)d_ws;

    k_main<<<BB * NF * CHUNKS, 256, 0, stream>>>(field, quad,
        (const float*)d_in[2], (const float*)d_in[3],
        (const float*)d_in[4], (const float*)d_in[5],
        (const float*)d_in[6], (const float*)d_in[7],
        (const float*)d_in[8], ws);
    k_final<<<(BB * NF * NK) / 256, 256, 0, stream>>>(ws, (float*)d_out);
}

// Round 9
// 231.188 us; speedup vs baseline: 1.0099x; 1.0099x over previous
//
#include <hip/hip_runtime.h>
#include <math.h>

// Problem constants (fixed by reference)
#define NF 8
#define NK 16
#define BB 32
#define YY 32
#define XX 32
#define PP 16
#define TT 8
#define YX (YY*XX)     // 1024
#define PT (PP*TT)     // 128
#define YXPT (YX*PT)   // 131072
#define CHUNKS 8
#define COLS_PER_BLOCK (YX/CHUNKS)        // 128
#define COLS_PER_WAVE  (COLS_PER_BLOCK/4) // 32
#define STEP           ((2*PT)/4)         // 64 float4s = 2 columns

// Workspace layout (float offsets)
#define QMEAN_OFF 0                            // [YXPT]             = 131072
#define ACC_OFF   (QMEAN_OFF + YXPT)           // [CHUNKS][BB*NF*NK] = 32768
#define INTG_OFF  (ACC_OFF + CHUNKS*BB*NF*NK)  // [4][NF*NK]         = 512

// ---------------------------------------------------------------------------
// FINAL (R9 = revert to R7, best measured: 232.3us).
// Session ledger: fills 155.5us fixed (harness poison, 2x77.7, invariant
// R0-R8). Controllable ~77us: k_main ~61 (274MB effective traffic incl.
// dirty-L3 eviction writebacks @ ~4.5 TB/s = ~71% mixed ceiling), qmean ~8,
// integral ~2.5, final ~1, gaps ~4.
// Probes closed: spill (R1/R2: launch_bounds 2nd arg -> 84-VGPR cap, 134MB
// scratch); occupancy (R7 waves_per_eu(4): null); pipeline depth (R6
// dist-8: regressed, 188 VGPR); qmean fusion (R6: regressed, occupancy
// dilution); accq fusion (R8: neutral, +VALU ate the launch savings).
// Wins kept: XCD remap (R2), Horner separability -20% VALU (R4),
// SGPR-pinned r[k] + epilogue c_k (R5), plain launch_bounds (R3).
// ---------------------------------------------------------------------------

// ---------------------------------------------------------------------------
// K1: qmean = quad.mean(axis=0). 1024 blocks, b-split 8 ways + LDS reduce.
// ---------------------------------------------------------------------------
__global__ __launch_bounds__(256) void k_qmean(const float* __restrict__ quad,
                                               float* __restrict__ ws) {
    const int tid = threadIdx.x, bx = blockIdx.x;
    __shared__ float4 sm[256];
    const int j4 = bx * 32 + (tid & 31);
    const int bg = tid >> 5;               // 8 groups of 4 b's
    const float4* q4 = (const float4*)quad;
    float4 a = make_float4(0.f, 0.f, 0.f, 0.f);
    #pragma unroll
    for (int i = 0; i < 4; ++i) {
        float4 v = q4[(size_t)(bg * 4 + i) * (YXPT / 4) + j4];
        a.x += v.x; a.y += v.y; a.z += v.z; a.w += v.w;
    }
    sm[tid] = a;
    __syncthreads();
    if (tid < 32) {
        float4 r = sm[tid];
        #pragma unroll
        for (int g = 1; g < 8; ++g) {
            float4 v = sm[tid + 32 * g];
            r.x += v.x; r.y += v.y; r.z += v.z; r.w += v.w;
        }
        r.x *= (1.f / BB); r.y *= (1.f / BB); r.z *= (1.f / BB); r.w *= (1.f / BB);
        ((float4*)(ws + QMEAN_OFF))[j4] = r;
    }
}

// ---------------------------------------------------------------------------
// K2: quarter-partials of integral[f,k]; block = (fk, quarter), no atomics.
// ---------------------------------------------------------------------------
__global__ __launch_bounds__(256) void k_integral(
    const float* __restrict__ mean_lat, const float* __restrict__ logstd_lat,
    const float* __restrict__ mean_lon, const float* __restrict__ logstd_lon,
    const float* __restrict__ mean_lev, const float* __restrict__ logstd_lev,
    const float* __restrict__ logtau, float* __restrict__ ws) {
    const int fk = blockIdx.x >> 2, qr = blockIdx.x & 3;
    const int tid = threadIdx.x;
    const float mlat = mean_lat[fk], islat = expf(-logstd_lat[fk]);
    const float mlon = mean_lon[fk], islon = expf(-logstd_lon[fk]);
    const float mlev = mean_lev[fk], islev = expf(-logstd_lev[fk]);
    const float itau = 1.f / (expf(logtau[fk]) + 1e-4f);

    __shared__ __align__(16) float wpt[PT];
    if (tid < PT) {
        const float cp = -1.f + 2.f * (float)(tid >> 3) / (PP - 1);
        const float zp = (cp - mlev) * islev;
        wpt[tid] = expf(-0.5f * zp * zp - (float)(tid & 7) * itau);
    }
    __syncthreads();

    const int yx = qr * 256 + tid;
    const float cy = -1.f + 2.f * (float)(yx >> 5) / (YY - 1);
    const float cx = -1.f + 2.f * (float)(yx & 31) / (XX - 1);
    const float zy = (cy - mlat) * islat;
    const float zx = (cx - mlon) * islon;
    const float wyx = expf(-0.5f * (zy * zy + zx * zx));

    const float4* q4 = (const float4*)(ws + QMEAN_OFF + (size_t)yx * PT);
    const float4* w4 = (const float4*)wpt;
    float s = 0.f;
    #pragma unroll
    for (int j = 0; j < PT / 4; ++j) {
        float4 w = w4[j], q = q4[j];
        s += w.x * q.x + w.y * q.y + w.z * q.z + w.w * q.w;
    }
    float partial = wyx * s;
    #pragma unroll
    for (int m = 32; m; m >>= 1) partial += __shfl_xor(partial, m);
    __shared__ float red[4];
    if ((tid & 63) == 0) red[tid >> 6] = partial;
    __syncthreads();
    if (tid == 0)
        ws[INTG_OFF + qr * (NF * NK) + fk] = red[0] + red[1] + red[2] + red[3];
}

// ---------------------------------------------------------------------------
// K3: main contraction. Block = (b, f, chunk of 128 cols); 4 waves.
// ---------------------------------------------------------------------------

#define KQ(WC, K) do {                                                          \
    float poly = fmaf(ga.w, r[K], ga.z);                                        \
    poly = fmaf(poly, r[K], ga.y);                                              \
    poly = fmaf(poly, r[K], ga.x);                                              \
    acc[K] = fmaf(WC, poly, acc[K]);                                            \
} while (0)

#define COLPAIR_COMPUTE(WVP) do {                                               \
    float4 ga;                                                                  \
    ga.x = fa.x*qa.x; ga.y = fa.y*qa.y; ga.z = fa.z*qa.z; ga.w = fa.w*qa.w;     \
    float4 w0 = (WVP)[0], w1 = (WVP)[1], w2 = (WVP)[2], w3 = (WVP)[3];          \
    KQ(w0.x, 0);  KQ(w0.y, 1);  KQ(w0.z, 2);  KQ(w0.w, 3);                      \
    KQ(w1.x, 4);  KQ(w1.y, 5);  KQ(w1.z, 6);  KQ(w1.w, 7);                      \
    KQ(w2.x, 8);  KQ(w2.y, 9);  KQ(w2.z, 10); KQ(w2.w, 11);                     \
    KQ(w3.x, 12); KQ(w3.y, 13); KQ(w3.z, 14); KQ(w3.w, 15);                     \
} while (0)

__global__ __launch_bounds__(256)
__attribute__((amdgpu_waves_per_eu(4)))
void k_main(
    const float* __restrict__ field, const float* __restrict__ quad,
    const float* __restrict__ mean_lat, const float* __restrict__ logstd_lat,
    const float* __restrict__ mean_lon, const float* __restrict__ logstd_lon,
    const float* __restrict__ mean_lev, const float* __restrict__ logstd_lev,
    const float* __restrict__ logtau, float* __restrict__ ws)
{
    const int bx = blockIdx.x;
    // XCD-aware remap: 8 f-sharers of one quad slice -> same XCD L2
    const int qg2 = bx >> 6, f = (bx >> 3) & 7, rr0 = bx & 7;
    const int bc = qg2 * 8 + rr0;
    const int b = bc >> 3, chunk = bc & 7;
    const int tid = threadIdx.x;
    const int wave = tid >> 6, L = tid & 63;
    const int half = L >> 5, qg = L & 31;

    const int colBase = chunk * COLS_PER_BLOCK + wave * COLS_PER_WAVE;
    const float4* fp = (const float4*)(field + (size_t)(b * NF + f) * YXPT + (size_t)colBase * PT) + L;
    const float4* qp = (const float4*)(quad  + (size_t)b * YXPT            + (size_t)colBase * PT) + L;

    // issue prologue global loads FIRST: they fly during the LDS table build
    float4 fbuf[4], qbuf[4];
    #pragma unroll
    for (int j = 0; j < 4; ++j) { fbuf[j] = fp[j * STEP]; qbuf[j] = qp[j * STEP]; }

    __shared__ __align__(16) float sw[COLS_PER_BLOCK * NK]; // 8 KB: [col][k]
    __shared__ float wptab[NK * PP];                        // 1 KB: [k][p]
    __shared__ float prm[NK][8];

    if (tid < NK) {
        const int fk = f * NK + tid;
        prm[tid][0] = mean_lat[fk];
        prm[tid][1] = expf(-logstd_lat[fk]);            // 1/std lat
        prm[tid][2] = mean_lon[fk];
        prm[tid][3] = expf(-logstd_lon[fk]);
        prm[tid][4] = mean_lev[fk];
        prm[tid][5] = expf(-logstd_lev[fk]);
        const float itau = 1.f / (expf(logtau[fk]) + 1e-4f);
        const float rk = expf(-itau);
        prm[tid][6] = rk;                               // r = exp(-1/tau)
        prm[tid][7] = rk * rk * rk * rk;                // r^4
    }
    __syncthreads();

    #pragma unroll
    for (int i = 0; i < 8; ++i) {       // sw[col][k] for this chunk
        const int e = i * 256 + tid;
        const int col = e >> 4, k = e & 15;
        const int yx = chunk * COLS_PER_BLOCK + col;
        const float cy = -1.f + 2.f * (float)(yx >> 5) / (YY - 1);
        const float cx = -1.f + 2.f * (float)(yx & 31) / (XX - 1);
        const float zy = (cy - prm[k][0]) * prm[k][1];
        const float zx = (cx - prm[k][2]) * prm[k][3];
        sw[col * NK + k] = expf(-0.5f * (zy * zy + zx * zx));
    }
    {   // wptab[k][p]: one expf per thread
        const int k = tid >> 4, p = tid & 15;
        const float cp = -1.f + 2.f * (float)p / (PP - 1);
        const float zp = (cp - prm[k][4]) * prm[k][5];
        wptab[tid] = expf(-0.5f * zp * zp);
    }
    __syncthreads();

    // r[k] is wave-uniform -> pin to SGPRs (v_fma takes one SGPR operand)
    float r[NK];
    #pragma unroll
    for (int k = 0; k < NK; ++k)
        r[k] = __int_as_float(__builtin_amdgcn_readfirstlane(__float_as_int(prm[k][6])));

    float acc[NK];
    #pragma unroll
    for (int k = 0; k < NK; ++k) acc[k] = 0.f;

    const float* swp = sw + (wave * COLS_PER_WAVE + half) * NK;

    // distance-4 pipeline, inner-unroll-4, peeled tail (no OOB prefetch)
    #pragma unroll 1
    for (int so = 0; so < 3; ++so) {
        fp += 4 * STEP; qp += 4 * STEP;
        #pragma unroll
        for (int j = 0; j < 4; ++j) {
            float4 fa = fbuf[j], qa = qbuf[j];
            fbuf[j] = fp[j * STEP]; qbuf[j] = qp[j * STEP];
            const float4* wvp = (const float4*)(swp + j * (2 * NK));
            COLPAIR_COMPUTE(wvp);
        }
        swp += 4 * (2 * NK);
    }
    #pragma unroll
    for (int j = 0; j < 4; ++j) {
        float4 fa = fbuf[j], qa = qbuf[j];
        const float4* wvp = (const float4*)(swp + j * (2 * NK));
        COLPAIR_COMPUTE(wvp);
    }

    // epilogue: apply factored per-lane constant c_k = wp[k][p] * r^t0
    // (computed HERE from LDS so it is never live across the main loop)
    {
        const int p = qg >> 1, hi = qg & 1;
        #pragma unroll
        for (int k = 0; k < NK; ++k) {
            const float wp = wptab[k * PP + p];
            const float ck = hi ? wp * prm[k][7] : wp;
            acc[k] *= ck;
        }
    }

    __shared__ float red[4][NK];
    #pragma unroll
    for (int k = 0; k < NK; ++k) {
        float v = acc[k];
        v += __shfl_xor(v, 32); v += __shfl_xor(v, 16); v += __shfl_xor(v, 8);
        v += __shfl_xor(v, 4);  v += __shfl_xor(v, 2);  v += __shfl_xor(v, 1);
        if (L == 0) red[wave][k] = v;
    }
    __syncthreads();
    if (tid < NK) {
        float s2 = red[0][tid] + red[1][tid] + red[2][tid] + red[3][tid];
        ws[ACC_OFF + chunk * (BB * NF * NK) + (b * NF + f) * NK + tid] = s2;
    }
}

// ---------------------------------------------------------------------------
// K4: out[b,f,k] = sum_c accP[c] / (1e-4 + sum_q intgP[q])
// ---------------------------------------------------------------------------
__global__ void k_final(const float* __restrict__ ws, float* __restrict__ out) {
    int i = blockIdx.x * 256 + threadIdx.x;
    if (i >= BB * NF * NK) return;
    float a = 0.f;
    #pragma unroll
    for (int c = 0; c < CHUNKS; ++c) a += ws[ACC_OFF + c * (BB * NF * NK) + i];
    const int fk = i & (NF * NK - 1);
    float g = 1e-4f;
    #pragma unroll
    for (int q = 0; q < 4; ++q) g += ws[INTG_OFF + q * (NF * NK) + fk];
    out[i] = a / g;
}

extern "C" void kernel_launch(void* const* d_in, const int* in_sizes, int n_in,
                              void* d_out, int out_size, void* d_ws, size_t ws_size,
                              hipStream_t stream) {
    const float* field = (const float*)d_in[0];
    const float* quad  = (const float*)d_in[1];
    float* ws = (float*)d_ws;

    k_qmean<<<1024, 256, 0, stream>>>(quad, ws);
    k_integral<<<NF * NK * 4, 256, 0, stream>>>(
        (const float*)d_in[2], (const float*)d_in[3],
        (const float*)d_in[4], (const float*)d_in[5],
        (const float*)d_in[6], (const float*)d_in[7],
        (const float*)d_in[8], ws);
    k_main<<<BB * NF * CHUNKS, 256, 0, stream>>>(field, quad,
        (const float*)d_in[2], (const float*)d_in[3],
        (const float*)d_in[4], (const float*)d_in[5],
        (const float*)d_in[6], (const float*)d_in[7],
        (const float*)d_in[8], ws);
    k_final<<<(BB * NF * NK + 255) / 256, 256, 0, stream>>>(ws, (float*)d_out);
}